// Round 8
// baseline (29.004 us; speedup 1.0000x reference)
//
#include <hip/hip_runtime.h>

// out[b,u] = tanh( exp( max_i x[b,i]*W[i,u] ) - 1 + bias[u] )
// exp monotonic -> max commutes -> max-times "GEMM" + transcendental epilogue.
//
// R8: x broadcast via LDS (ds_read, in-order, partial lgkmcnt waits) instead of
// the scalar pipe (s_load is out-of-order -> forced lgkmcnt(0) drains = the
// R4-R7 invariant stall). W stays VGPR-resident (pinned). All-VGPR pk_mul.
//   Block = 16 waves x 64 units (lane = unit), band = 8 rows.
//   Wave wv owns k-chunk [wv*32, wv*32+32). Partials combined via LDS.
//   48 KB LDS, <=64 VGPR -> 2 blocks/CU = 8 waves/SIMD.

#define BATCH 2048
#define INDIM 512
#define UNITS 512

#define KC 32   // k-chunk per wave
#define RB 8    // rows per block
#define NW 16   // waves per block (NW*KC == INDIM)

typedef float v2f __attribute__((ext_vector_type(2)));

__global__ __launch_bounds__(1024, 8) void maxexp_kernel(
    const float* __restrict__ x,     // [BATCH][INDIM]
    const float* __restrict__ W,     // [INDIM][UNITS]
    const float* __restrict__ bias,  // [UNITS]
    float* __restrict__ out)         // [BATCH][UNITS]
{
    __shared__ float xs[RB][INDIM];     // 16 KB : x band (broadcast source)
    __shared__ float part[RB][NW][64];  // 32 KB : per-wave partial maxima

    // bijective XCD swizzle: XCD (f&7) owns 32 contiguous bands x all 8 u-tiles
    const int f    = blockIdx.x;                       // 0..2047
    const int band = (f & 7) * 32 + ((f >> 3) & 31);   // 0..255
    const int ut   = f >> 8;                           // 0..7

    const int tid  = threadIdx.x;
    const int lane = tid & 63;
    const int wv   = __builtin_amdgcn_readfirstlane(tid >> 6); // 0..15
    const int u    = ut * 64 + lane;     // unit (per-lane)
    const int k0   = wv * KC;            // k-chunk base (uniform)
    const int b0   = band * RB;          // first row (uniform)

    // ---- stage x band: 8 rows x 512 floats, 1024 threads x 1 float4 ----
    {
        const float4 v = *reinterpret_cast<const float4*>(
            x + (size_t)b0 * INDIM + (size_t)tid * 4);
        *reinterpret_cast<float4*>(&xs[0][0] + (size_t)tid * 4) = v;
    }

    // ---- preload W chunk as v2f pairs, pin in VGPRs ----
    v2f wp[KC / 2];
    {
        const float* wb = W + (size_t)k0 * UNITS + u;
#pragma unroll
        for (int j = 0; j < KC / 2; ++j) {
            v2f t;
            t.x = wb[(size_t)(2 * j)     * UNITS];
            t.y = wb[(size_t)(2 * j + 1) * UNITS];
            wp[j] = t;
        }
    }
#pragma unroll
    for (int j = 0; j < KC / 2; ++j) asm("" : "+v"(wp[j]));

    __syncthreads();   // xs ready

    // ---- compute: 8 rows x 32 k, LDS-broadcast x * VGPR W ----
#pragma unroll
    for (int t = 0; t < RB; ++t) {
        const float4* xq = reinterpret_cast<const float4*>(&xs[t][k0]);
        float m0 = -3.4e38f, m1 = -3.4e38f;   // two chains
#pragma unroll
        for (int q4 = 0; q4 < KC / 4; ++q4) {  // 8 x ds_read_b128 (uniform addr)
            const float4 q = xq[q4];
            v2f a0, a1, p0, p1;
            a0.x = q.x; a0.y = q.y;
            a1.x = q.z; a1.y = q.w;
            asm("v_pk_mul_f32 %0, %1, %2" : "=v"(p0) : "v"(a0), "v"(wp[2 * q4]));
            asm("v_pk_mul_f32 %0, %1, %2" : "=v"(p1) : "v"(a1), "v"(wp[2 * q4 + 1]));
            m0 = fmaxf(fmaxf(m0, p0.x), p0.y);   // -> v_max3_f32
            m1 = fmaxf(fmaxf(m1, p1.x), p1.y);
        }
        part[t][wv][lane] = fmaxf(m0, m1);
    }

    __syncthreads();   // partials ready

    // ---- waves 0..7: combine 16 partials, epilogue, store one row each ----
    if (wv < RB) {
        const int t = wv;
        float m = -3.4e38f;
#pragma unroll
        for (int j = 0; j < NW; j += 2)
            m = fmaxf(fmaxf(m, part[t][j][lane]), part[t][j + 1][lane]);
        const float pp = __expf(m) - 1.0f + bias[u];
        const float e  = __expf(2.0f * pp);
        out[(size_t)(b0 + t) * UNITS + u] = 1.0f - 2.0f / (e + 1.0f);
    }
}

extern "C" void kernel_launch(void* const* d_in, const int* in_sizes, int n_in,
                              void* d_out, int out_size, void* d_ws, size_t ws_size,
                              hipStream_t stream) {
    const float* x    = (const float*)d_in[0];
    const float* W    = (const float*)d_in[1];
    const float* bias = (const float*)d_in[2];
    float* out = (float*)d_out;

    dim3 grid(BATCH / RB * (UNITS / 64));   // 256 bands * 8 u-tiles = 2048 blocks
    dim3 block(1024);                       // 16 waves
    maxexp_kernel<<<grid, block, 0, stream>>>(x, W, bias, out);
}

// Round 9
// 28.789 us; speedup vs baseline: 1.0075x; 1.0075x over previous
//
#include <hip/hip_runtime.h>

// out[b,u] = tanh( exp( max_i x[b,i]*W[i,u] ) - 1 + bias[u] )
// exp monotonic -> max commutes -> max-times "GEMM" + transcendental epilogue.
//
// R9: PERSISTENT blocks (512 = exactly 2/CU, one generation). The R4-R8
// plateau was per-block prologue (W preload + stage + barrier latency)
// ~= per-block compute; here the prologue amortizes over 4 bands.
//   Block = 8 waves x 64 units (lane = unit). Wave wv pins W[wv*64..+63][u]
//   as 32 v2f in VGPRs. Per band (8 rows): global_load_lds-stage next band
//   || compute current from LDS (uniform-addr broadcast ds_read_b128),
//   barrier, 8-way combine (one row per wave) + exp/tanh + store, barrier.

#define BATCH 2048
#define INDIM 512
#define UNITS 512

#define KC 64     // k-chunk per wave (W-resident VGPRs, 8-way k-split)
#define RB 8      // rows per band
#define NW 8      // waves per block
#define NBANDS 4  // bands per block

typedef float v2f __attribute__((ext_vector_type(2)));

__global__ __launch_bounds__(512, 4) void maxexp_kernel(
    const float* __restrict__ x,     // [BATCH][INDIM]
    const float* __restrict__ W,     // [INDIM][UNITS]
    const float* __restrict__ bias,  // [UNITS]
    float* __restrict__ out)         // [BATCH][UNITS]
{
    __shared__ float xs[2][RB][INDIM];   // 32 KB : double-buffered x bands
    __shared__ float part[RB][NW][64];   // 16 KB : per-wave partial maxima

    // XCD swizzle: XCD (f&7) owns rows [xcd*256, +256) across all u-tiles.
    const int f     = blockIdx.x;        // 0..511
    const int xcd   = f & 7;
    const int g     = f >> 3;            // 0..63
    const int ut    = g & 7;             // u-tile 0..7
    const int bgrp  = g >> 3;            // 0..7
    const int band0 = xcd * 32 + bgrp * NBANDS;   // first band (of 256)

    const int tid  = threadIdx.x;
    const int lane = tid & 63;
    const int wv   = __builtin_amdgcn_readfirstlane(tid >> 6);  // 0..7
    const int u    = ut * 64 + lane;     // unit (per-lane)
    const int k0   = wv * KC;            // k-chunk base (uniform)

    // ---- one-time W preload: 32 v2f pairs, pinned in VGPRs ----
    v2f wp[KC / 2];
    {
        const float* wb = W + (size_t)k0 * UNITS + u;
#pragma unroll
        for (int j = 0; j < KC / 2; ++j) {
            v2f t;
            t.x = wb[(size_t)(2 * j)     * UNITS];
            t.y = wb[(size_t)(2 * j + 1) * UNITS];
            wp[j] = t;
        }
    }
#pragma unroll
    for (int j = 0; j < KC / 2; ++j) asm("" : "+v"(wp[j]));

    const float bv = bias[u];

    // wave wv stages row wv of a band: 2KB = 2 x (64 lanes x 16B), HBM->LDS
#define STAGE(buf, bd)                                                        \
    {                                                                         \
        const float* src_ = x + (size_t)((bd) * RB + wv) * INDIM + lane * 4;  \
        float* dst_ = &xs[buf][wv][0];                                        \
        __builtin_amdgcn_global_load_lds(                                     \
            (const __attribute__((address_space(1))) unsigned int*)src_,      \
            (__attribute__((address_space(3))) unsigned int*)dst_, 16, 0, 0); \
        __builtin_amdgcn_global_load_lds(                                     \
            (const __attribute__((address_space(1))) unsigned int*)(src_ + 256), \
            (__attribute__((address_space(3))) unsigned int*)(dst_ + 256), 16, 0, 0); \
    }

    STAGE(0, band0);
    __syncthreads();   // barrier drains vmcnt -> band 0 staged

#pragma unroll 1
    for (int t = 0; t < NBANDS; ++t) {
        const int band = band0 + t;
        const int cur  = t & 1;

        if (t + 1 < NBANDS) STAGE(cur ^ 1, band + 1);   // prefetch next band

        // ---- compute: 8 rows x 64 k from LDS broadcast * pinned W ----
#pragma unroll
        for (int r = 0; r < RB; ++r) {
            const float4* xq = reinterpret_cast<const float4*>(&xs[cur][r][k0]);
            float m0 = -3.4e38f, m1 = -3.4e38f;
#pragma unroll
            for (int q = 0; q < KC / 4; ++q) {   // 16 x ds_read_b128 (uniform)
                const float4 a = xq[q];
                v2f a0, a1, p0, p1;
                a0.x = a.x; a0.y = a.y;
                a1.x = a.z; a1.y = a.w;
                asm("v_pk_mul_f32 %0, %1, %2" : "=v"(p0) : "v"(a0), "v"(wp[2 * q]));
                asm("v_pk_mul_f32 %0, %1, %2" : "=v"(p1) : "v"(a1), "v"(wp[2 * q + 1]));
                m0 = fmaxf(fmaxf(m0, p0.x), p0.y);   // -> v_max3_f32
                m1 = fmaxf(fmaxf(m1, p1.x), p1.y);
            }
            part[r][wv][lane] = fmaxf(m0, m1);
        }

        __syncthreads();   // partials ready

        // ---- combine: wave wv reduces row wv, epilogue, store ----
        {
            float m = -3.4e38f;
#pragma unroll
            for (int j = 0; j < NW; j += 2)
                m = fmaxf(fmaxf(m, part[wv][j][lane]), part[wv][j + 1][lane]);
            const float pp = __expf(m) - 1.0f + bv;
            const float e  = __expf(2.0f * pp);
            out[(size_t)(band * RB + wv) * UNITS + u] = 1.0f - 2.0f / (e + 1.0f);
        }

        __syncthreads();   // part free + next band staged (vmcnt drained)
    }
#undef STAGE
}

extern "C" void kernel_launch(void* const* d_in, const int* in_sizes, int n_in,
                              void* d_out, int out_size, void* d_ws, size_t ws_size,
                              hipStream_t stream) {
    const float* x    = (const float*)d_in[0];
    const float* W    = (const float*)d_in[1];
    const float* bias = (const float*)d_in[2];
    float* out = (float*)d_out;

    dim3 grid(512);    // 8 XCD-bands x 8 u-tiles x 8 band-groups = 2 blocks/CU
    dim3 block(512);   // 8 waves
    maxexp_kernel<<<grid, block, 0, stream>>>(x, W, bias, out);
}

// Round 10
// 27.029 us; speedup vs baseline: 1.0731x; 1.0651x over previous
//
#include <hip/hip_runtime.h>

// out[b,u] = tanh( exp( max_i x[b,i]*W[i,u] ) - 1 + bias[u] )
// exp monotonic -> max commutes -> max-times "GEMM" + transcendental epilogue.
//
// R10: R7 dataflow with register pressure engineered UNDER the VGPR cap.
// R4-R9 post-mortem: VGPR_Count=48 < pinned-array size proves W was silently
// SPILLED TO SCRATCH (launch-bounds cap < true pressure); hot loops re-read W
// from L2-backed scratch at ~200cy -> the 26-31us plateau, insensitive to
// every structural change. Here: wp(32) + acc(8) + temps(~16) = ~56 <= 64,
// so __launch_bounds__(1024,8) holds with ZERO spill: 8 waves/SIMD, zero
// vector-memory and zero scratch in the steady loop.
//   Block = 16 waves x 64 units (lane = unit), RB = 8 rows.
//   Wave wv owns k-chunk [wv*32, +32): W as 16 v2f in VGPRs (for real now).
//   x rows wave-uniform -> s_load to SGPRs, consumed as v_pk_mul_f32 "s" src.
//   16-way k-combine via LDS; waves 0..7 do epilogue for one row each.

#define BATCH 2048
#define INDIM 512
#define UNITS 512

#define KC 32   // k-chunk per wave
#define RB 8    // rows per block
#define NW 16   // waves per block (NW*KC == INDIM)

typedef float v2f __attribute__((ext_vector_type(2)));

__global__ __launch_bounds__(1024, 8) void maxexp_kernel(
    const float* __restrict__ x,     // [BATCH][INDIM]
    const float* __restrict__ W,     // [INDIM][UNITS]
    const float* __restrict__ bias,  // [UNITS]
    float* __restrict__ out)         // [BATCH][UNITS]
{
    __shared__ float part[RB][NW][64];   // 32 KB

    // bijective XCD swizzle: XCD (f&7) owns 32 contiguous bands x all u-tiles.
    const int f    = blockIdx.x;                       // 0..2047
    const int band = (f & 7) * 32 + ((f >> 3) & 31);   // 0..255
    const int ut   = f >> 8;                           // 0..7

    const int lane = threadIdx.x & 63;
    const int wv   = __builtin_amdgcn_readfirstlane(threadIdx.x >> 6); // 0..15
    const int u    = ut * 64 + lane;     // unit (per-lane)
    const int k0   = wv * KC;            // k-chunk base (uniform)
    const int b0   = band * RB;          // first row (uniform)

    // ---- preload W chunk as 16 v2f pairs (32 VGPRs, coalesced loads) ----
    v2f wp[KC / 2];
    {
        const float* wb = W + (size_t)k0 * UNITS + u;
#pragma unroll
        for (int j = 0; j < KC / 2; ++j) {
            v2f t;
            t.x = wb[(size_t)(2 * j)     * UNITS];
            t.y = wb[(size_t)(2 * j + 1) * UNITS];
            wp[j] = t;
        }
    }
#pragma unroll
    for (int j = 0; j < KC / 2; ++j) asm("" : "+v"(wp[j]));

    const float* xb = x + (size_t)b0 * INDIM + k0;   // uniform base

    float acc[RB];
#pragma unroll
    for (int t = 0; t < RB; ++t) {
        const v2f* xr = reinterpret_cast<const v2f*>(xb + (size_t)t * INDIM);
        float m0 = -3.4e38f, m1 = -3.4e38f;   // two independent chains
#pragma unroll
        for (int j = 0; j < KC / 2; j += 2) {
            v2f p0, p1;
            // x pair from SGPRs (64-bit scalar operand), W pair from VGPRs
            asm("v_pk_mul_f32 %0, %1, %2" : "=v"(p0) : "s"(xr[j]),     "v"(wp[j]));
            asm("v_pk_mul_f32 %0, %1, %2" : "=v"(p1) : "s"(xr[j + 1]), "v"(wp[j + 1]));
            m0 = fmaxf(fmaxf(m0, p0.x), p0.y);   // -> v_max3_f32
            m1 = fmaxf(fmaxf(m1, p1.x), p1.y);
        }
        acc[t] = fmaxf(m0, m1);
    }

    // ---- 16-way cross-wave max combine via LDS (single barrier) ----
#pragma unroll
    for (int t = 0; t < RB; ++t) part[t][wv][lane] = acc[t];
    __syncthreads();

    // waves 0..7: reduce one row each, epilogue, store
    if (wv < RB) {
        const int t = wv;
        float m = -3.4e38f;
#pragma unroll
        for (int j = 0; j < NW; j += 2)
            m = fmaxf(fmaxf(m, part[t][j][lane]), part[t][j + 1][lane]);
        const float pp = __expf(m) - 1.0f + bias[u];
        const float e  = __expf(2.0f * pp);
        out[(size_t)(b0 + t) * UNITS + u] = 1.0f - 2.0f / (e + 1.0f);
    }
}

extern "C" void kernel_launch(void* const* d_in, const int* in_sizes, int n_in,
                              void* d_out, int out_size, void* d_ws, size_t ws_size,
                              hipStream_t stream) {
    const float* x    = (const float*)d_in[0];
    const float* W    = (const float*)d_in[1];
    const float* bias = (const float*)d_in[2];
    float* out = (float*)d_out;

    dim3 grid(BATCH / RB * (UNITS / 64));   // 256 bands * 8 u-tiles = 2048 blocks
    dim3 block(1024);                       // 16 waves
    maxexp_kernel<<<grid, block, 0, stream>>>(x, W, bias, out);
}